// Round 2
// baseline (101.488 us; speedup 1.0000x reference)
//
#include <hip/hip_runtime.h>

#define V 64
#define W 5
#define G 80
#define O 80
#define NROT 16
#define EPSV 1e-5f
#define NLOG2E (-1.4426950408889634f)

// ============================================================================
// Kernel A: compute normalized descriptors desc[p][w][j][g][4] -> d_ws
// One block per point, 320 threads: g = tid%80, j = tid/80 (k = 4j..4j+3).
// ============================================================================
__global__ __launch_bounds__(320) void desc_kernel(
    const float* __restrict__ feat,      // [NP][V][W]
    const float* __restrict__ rho,       // [NP][V]
    const float* __restrict__ theta,     // [NP][V]
    const float* __restrict__ mask,      // [NP][V]
    const float* __restrict__ mu_rho,    // [W][G]
    const float* __restrict__ mu_theta,  // [W][G]
    const float* __restrict__ sig_rho,   // [W][G]
    const float* __restrict__ sig_theta, // [W][G]
    float* __restrict__ ws)              // desc [NP][W][4][G][4]
{
    __shared__ float s_rhom[V][2];         // (rho, mask? 0 : -1e30)
    __shared__ float s_featT[V][8];        // feat[v][w], padded
    __shared__ float s_th[V][NROT];        // rotated theta per (v,k)

    const int tid = threadIdx.x;
    const int p = blockIdx.x;
    const int g = tid % G;   // 0..79
    const int j = tid / G;   // 0..3

    if (tid < V) {
        s_rhom[tid][0] = rho[p * V + tid];
        s_rhom[tid][1] = (mask[p * V + tid] != 0.0f) ? 0.0f : -1e30f;
    }
    if (tid < V * W) {
        int v = tid / W, w = tid % W;
        s_featT[v][w] = feat[p * V * W + tid];
    }
    const float kstep = 0.39269908169872414f;      // 2*pi/16
    const float two_pi = 6.283185307179586f;
    const float inv_two_pi = 0.15915494309189535f;
    for (int i = tid; i < V * NROT; i += 320) {
        int v = i >> 4, k = i & 15;
        float x = theta[p * V + v] + (float)k * kstep;
        x = x - floorf(x * inv_two_pi) * two_pi;   // jnp.mod(x, 2pi)
        s_th[v][k] = x;
    }

    int pred = (mu_rho  [(1 + j) * G + g] == mu_rho  [g]) &&
               (mu_theta[(1 + j) * G + g] == mu_theta[g]) &&
               (sig_rho [(1 + j) * G + g] == sig_rho [g]) &&
               (sig_theta[(1 + j) * G + g] == sig_theta[g]);
    const int uni = __syncthreads_and(pred);

    float* dbase = ws + (size_t)p * (W * 4 * G * 4);   // [w][j][g][4]

    if (uni) {
        const float mu_r = mu_rho[g];
        const float sr   = sig_rho[g];
        const float c_sr = NLOG2E / (sr * sr + EPSV);
        const float mu_t = mu_theta[g];
        const float st   = sig_theta[g];
        const float c_st = NLOG2E / (st * st + EPSV);

        float den[4] = {0.f, 0.f, 0.f, 0.f};
        float num[5][4];
        #pragma unroll
        for (int w = 0; w < W; ++w)
            #pragma unroll
            for (int kk = 0; kk < 4; ++kk) num[w][kk] = 0.f;

        #pragma unroll 4
        for (int v = 0; v < V; ++v) {
            float2 rm = *(const float2*)(&s_rhom[v][0]);
            float dr = rm.x - mu_r;
            float argr = fmaf(dr * dr, c_sr, rm.y);
            float4 fA = *(const float4*)(&s_featT[v][0]);
            float f4v = s_featT[v][4];
            float4 th4 = *(const float4*)(&s_th[v][j * 4]);
            float tv[4] = {th4.x, th4.y, th4.z, th4.w};
            #pragma unroll
            for (int kk = 0; kk < 4; ++kk) {
                float t = tv[kk] - mu_t;
                float e = __builtin_amdgcn_exp2f(fmaf(t * t, c_st, argr));
                den[kk] += e;
                num[0][kk] = fmaf(e, fA.x, num[0][kk]);
                num[1][kk] = fmaf(e, fA.y, num[1][kk]);
                num[2][kk] = fmaf(e, fA.z, num[2][kk]);
                num[3][kk] = fmaf(e, fA.w, num[3][kk]);
                num[4][kk] = fmaf(e, f4v,  num[4][kk]);
            }
        }
        float rd[4];
        #pragma unroll
        for (int kk = 0; kk < 4; ++kk)
            rd[kk] = __builtin_amdgcn_rcpf(den[kk] + EPSV);
        #pragma unroll
        for (int w = 0; w < W; ++w) {
            float4 dv = make_float4(num[w][0] * rd[0], num[w][1] * rd[1],
                                    num[w][2] * rd[2], num[w][3] * rd[3]);
            *(float4*)(dbase + ((w * 4 + j) * G + g) * 4) = dv;
        }
    } else {
        #pragma unroll 1
        for (int w = 0; w < W; ++w) {
            const float mu_r = mu_rho[w * G + g];
            const float sr   = sig_rho[w * G + g];
            const float c_sr = NLOG2E / (sr * sr + EPSV);
            const float mu_t = mu_theta[w * G + g];
            const float st   = sig_theta[w * G + g];
            const float c_st = NLOG2E / (st * st + EPSV);
            float den[4] = {0.f, 0.f, 0.f, 0.f};
            float nm[4]  = {0.f, 0.f, 0.f, 0.f};
            for (int v = 0; v < V; ++v) {
                float2 rm = *(const float2*)(&s_rhom[v][0]);
                float dr = rm.x - mu_r;
                float argr = fmaf(dr * dr, c_sr, rm.y);
                float fw = s_featT[v][w];
                float4 th4 = *(const float4*)(&s_th[v][j * 4]);
                float tv[4] = {th4.x, th4.y, th4.z, th4.w};
                #pragma unroll
                for (int kk = 0; kk < 4; ++kk) {
                    float t = tv[kk] - mu_t;
                    float e = __builtin_amdgcn_exp2f(fmaf(t * t, c_st, argr));
                    den[kk] += e;
                    nm[kk] = fmaf(e, fw, nm[kk]);
                }
            }
            float4 dv;
            dv.x = nm[0] * __builtin_amdgcn_rcpf(den[0] + EPSV);
            dv.y = nm[1] * __builtin_amdgcn_rcpf(den[1] + EPSV);
            dv.z = nm[2] * __builtin_amdgcn_rcpf(den[2] + EPSV);
            dv.w = nm[3] * __builtin_amdgcn_rcpf(den[3] + EPSV);
            *(float4*)(dbase + ((w * 4 + j) * G + g) * 4) = dv;
        }
    }
}

// ============================================================================
// Kernel B: out[p][w][o] = max_k (sum_g desc[w][g][k]*Wc[w][g][o]) + bc[w][o]
// One block per point, 400 threads = exactly one output each. No LDS.
// ============================================================================
__global__ __launch_bounds__(400) void out_kernel(
    const float* __restrict__ ws,        // desc [NP][W][4][G][4]
    const float* __restrict__ Wc,        // [W][G][O]
    const float* __restrict__ bc,        // [W][O]
    float* __restrict__ out)             // [NP][W][O]
{
    const int idx = threadIdx.x;         // 0..399
    const int p = blockIdx.x;
    const int w = idx / O, o = idx % O;

    const float* dbase = ws + (size_t)p * (W * 4 * G * 4) + w * (4 * G * 4);
    const float* wp = Wc + w * G * O + o;

    float acc[NROT];
    #pragma unroll
    for (int k = 0; k < NROT; ++k) acc[k] = 0.f;

    #pragma unroll 4
    for (int gg = 0; gg < G; ++gg) {
        float wcv = wp[gg * O];                          // coalesced over o
        float4 d0 = *(const float4*)(dbase + (0 * G + gg) * 4);  // broadcast
        float4 d1 = *(const float4*)(dbase + (1 * G + gg) * 4);
        float4 d2 = *(const float4*)(dbase + (2 * G + gg) * 4);
        float4 d3 = *(const float4*)(dbase + (3 * G + gg) * 4);
        acc[0]  = fmaf(d0.x, wcv, acc[0]);
        acc[1]  = fmaf(d0.y, wcv, acc[1]);
        acc[2]  = fmaf(d0.z, wcv, acc[2]);
        acc[3]  = fmaf(d0.w, wcv, acc[3]);
        acc[4]  = fmaf(d1.x, wcv, acc[4]);
        acc[5]  = fmaf(d1.y, wcv, acc[5]);
        acc[6]  = fmaf(d1.z, wcv, acc[6]);
        acc[7]  = fmaf(d1.w, wcv, acc[7]);
        acc[8]  = fmaf(d2.x, wcv, acc[8]);
        acc[9]  = fmaf(d2.y, wcv, acc[9]);
        acc[10] = fmaf(d2.z, wcv, acc[10]);
        acc[11] = fmaf(d2.w, wcv, acc[11]);
        acc[12] = fmaf(d3.x, wcv, acc[12]);
        acc[13] = fmaf(d3.y, wcv, acc[13]);
        acc[14] = fmaf(d3.z, wcv, acc[14]);
        acc[15] = fmaf(d3.w, wcv, acc[15]);
    }
    float m = acc[0];
    #pragma unroll
    for (int k = 1; k < NROT; ++k) m = fmaxf(m, acc[k]);
    out[p * W * O + idx] = m + bc[idx];
}

// ============================================================================
// Fallback: round-1 single-kernel (used only if ws_size is too small)
// ============================================================================
__global__ __launch_bounds__(320) void conv_kernel(
    const float* __restrict__ feat, const float* __restrict__ rho,
    const float* __restrict__ theta, const float* __restrict__ mask,
    const float* __restrict__ mu_rho, const float* __restrict__ mu_theta,
    const float* __restrict__ sig_rho, const float* __restrict__ sig_theta,
    const float* __restrict__ Wc, const float* __restrict__ bc,
    float* __restrict__ out)
{
    __shared__ float s_rhom[V][2];
    __shared__ float s_featT[V][8];
    __shared__ float s_th[V][NROT];
    __shared__ float s_desc[W][G][NROT];

    const int tid = threadIdx.x;
    const int p = blockIdx.x;
    const int g = tid % G;
    const int j = tid / G;

    if (tid < V) {
        s_rhom[tid][0] = rho[p * V + tid];
        s_rhom[tid][1] = (mask[p * V + tid] != 0.0f) ? 0.0f : -1e30f;
    }
    if (tid < V * W) {
        int v = tid / W, w = tid % W;
        s_featT[v][w] = feat[p * V * W + tid];
    }
    const float kstep = 0.39269908169872414f;
    const float two_pi = 6.283185307179586f;
    const float inv_two_pi = 0.15915494309189535f;
    for (int i = tid; i < V * NROT; i += 320) {
        int v = i >> 4, k = i & 15;
        float x = theta[p * V + v] + (float)k * kstep;
        x = x - floorf(x * inv_two_pi) * two_pi;
        s_th[v][k] = x;
    }
    int pred = (mu_rho  [(1 + j) * G + g] == mu_rho  [g]) &&
               (mu_theta[(1 + j) * G + g] == mu_theta[g]) &&
               (sig_rho [(1 + j) * G + g] == sig_rho [g]) &&
               (sig_theta[(1 + j) * G + g] == sig_theta[g]);
    const int uni = __syncthreads_and(pred);

    if (uni) {
        const float mu_r = mu_rho[g];
        const float sr   = sig_rho[g];
        const float c_sr = NLOG2E / (sr * sr + EPSV);
        const float mu_t = mu_theta[g];
        const float st   = sig_theta[g];
        const float c_st = NLOG2E / (st * st + EPSV);
        float den[4] = {0.f, 0.f, 0.f, 0.f};
        float num[5][4];
        #pragma unroll
        for (int w = 0; w < W; ++w)
            #pragma unroll
            for (int kk = 0; kk < 4; ++kk) num[w][kk] = 0.f;
        #pragma unroll 4
        for (int v = 0; v < V; ++v) {
            float2 rm = *(const float2*)(&s_rhom[v][0]);
            float dr = rm.x - mu_r;
            float argr = fmaf(dr * dr, c_sr, rm.y);
            float4 fA = *(const float4*)(&s_featT[v][0]);
            float f4v = s_featT[v][4];
            float4 th4 = *(const float4*)(&s_th[v][j * 4]);
            float tv[4] = {th4.x, th4.y, th4.z, th4.w};
            #pragma unroll
            for (int kk = 0; kk < 4; ++kk) {
                float t = tv[kk] - mu_t;
                float e = __builtin_amdgcn_exp2f(fmaf(t * t, c_st, argr));
                den[kk] += e;
                num[0][kk] = fmaf(e, fA.x, num[0][kk]);
                num[1][kk] = fmaf(e, fA.y, num[1][kk]);
                num[2][kk] = fmaf(e, fA.z, num[2][kk]);
                num[3][kk] = fmaf(e, fA.w, num[3][kk]);
                num[4][kk] = fmaf(e, f4v,  num[4][kk]);
            }
        }
        float rd[4];
        #pragma unroll
        for (int kk = 0; kk < 4; ++kk)
            rd[kk] = __builtin_amdgcn_rcpf(den[kk] + EPSV);
        #pragma unroll
        for (int w = 0; w < W; ++w) {
            float4 dv = make_float4(num[w][0] * rd[0], num[w][1] * rd[1],
                                    num[w][2] * rd[2], num[w][3] * rd[3]);
            *(float4*)(&s_desc[w][g][j * 4]) = dv;
        }
    } else {
        #pragma unroll 1
        for (int w = 0; w < W; ++w) {
            const float mu_r = mu_rho[w * G + g];
            const float sr   = sig_rho[w * G + g];
            const float c_sr = NLOG2E / (sr * sr + EPSV);
            const float mu_t = mu_theta[w * G + g];
            const float st   = sig_theta[w * G + g];
            const float c_st = NLOG2E / (st * st + EPSV);
            float den[4] = {0.f, 0.f, 0.f, 0.f};
            float nm[4]  = {0.f, 0.f, 0.f, 0.f};
            for (int v = 0; v < V; ++v) {
                float2 rm = *(const float2*)(&s_rhom[v][0]);
                float dr = rm.x - mu_r;
                float argr = fmaf(dr * dr, c_sr, rm.y);
                float fw = s_featT[v][w];
                float4 th4 = *(const float4*)(&s_th[v][j * 4]);
                float tv[4] = {th4.x, th4.y, th4.z, th4.w};
                #pragma unroll
                for (int kk = 0; kk < 4; ++kk) {
                    float t = tv[kk] - mu_t;
                    float e = __builtin_amdgcn_exp2f(fmaf(t * t, c_st, argr));
                    den[kk] += e;
                    nm[kk] = fmaf(e, fw, nm[kk]);
                }
            }
            float4 dv;
            dv.x = nm[0] * __builtin_amdgcn_rcpf(den[0] + EPSV);
            dv.y = nm[1] * __builtin_amdgcn_rcpf(den[1] + EPSV);
            dv.z = nm[2] * __builtin_amdgcn_rcpf(den[2] + EPSV);
            dv.w = nm[3] * __builtin_amdgcn_rcpf(den[3] + EPSV);
            *(float4*)(&s_desc[w][g][j * 4]) = dv;
        }
    }
    __syncthreads();
    for (int idx = tid; idx < W * O; idx += 320) {
        const int w = idx / O, o = idx % O;
        const float* wp = Wc + w * G * O + o;
        float acc[NROT];
        #pragma unroll
        for (int k = 0; k < NROT; ++k) acc[k] = 0.f;
        #pragma unroll 4
        for (int gg = 0; gg < G; ++gg) {
            float wcv = wp[gg * O];
            const float* dp = &s_desc[w][gg][0];
            float4 d0 = *(const float4*)(dp + 0);
            float4 d1 = *(const float4*)(dp + 4);
            float4 d2 = *(const float4*)(dp + 8);
            float4 d3 = *(const float4*)(dp + 12);
            acc[0]  = fmaf(d0.x, wcv, acc[0]);
            acc[1]  = fmaf(d0.y, wcv, acc[1]);
            acc[2]  = fmaf(d0.z, wcv, acc[2]);
            acc[3]  = fmaf(d0.w, wcv, acc[3]);
            acc[4]  = fmaf(d1.x, wcv, acc[4]);
            acc[5]  = fmaf(d1.y, wcv, acc[5]);
            acc[6]  = fmaf(d1.z, wcv, acc[6]);
            acc[7]  = fmaf(d1.w, wcv, acc[7]);
            acc[8]  = fmaf(d2.x, wcv, acc[8]);
            acc[9]  = fmaf(d2.y, wcv, acc[9]);
            acc[10] = fmaf(d2.z, wcv, acc[10]);
            acc[11] = fmaf(d2.w, wcv, acc[11]);
            acc[12] = fmaf(d3.x, wcv, acc[12]);
            acc[13] = fmaf(d3.y, wcv, acc[13]);
            acc[14] = fmaf(d3.z, wcv, acc[14]);
            acc[15] = fmaf(d3.w, wcv, acc[15]);
        }
        float m = acc[0];
        #pragma unroll
        for (int k = 1; k < NROT; ++k) m = fmaxf(m, acc[k]);
        out[p * W * O + idx] = m + bc[idx];
    }
}

extern "C" void kernel_launch(void* const* d_in, const int* in_sizes, int n_in,
                              void* d_out, int out_size, void* d_ws, size_t ws_size,
                              hipStream_t stream) {
    const float* feat      = (const float*)d_in[0];
    const float* rho       = (const float*)d_in[1];
    const float* theta     = (const float*)d_in[2];
    const float* mask      = (const float*)d_in[3];
    const float* mu_rho    = (const float*)d_in[4];
    const float* mu_theta  = (const float*)d_in[5];
    const float* sig_rho   = (const float*)d_in[6];
    const float* sig_theta = (const float*)d_in[7];
    const float* Wc        = (const float*)d_in[8];
    const float* bc        = (const float*)d_in[9];
    float* outp            = (float*)d_out;

    const int np = in_sizes[1] / V;   // B*N points (rho is [B,N,V])
    const size_t desc_bytes = (size_t)np * W * 4 * G * 4 * sizeof(float);

    if (ws_size >= desc_bytes) {
        float* ws = (float*)d_ws;
        desc_kernel<<<np, 320, 0, stream>>>(feat, rho, theta, mask, mu_rho,
                                            mu_theta, sig_rho, sig_theta, ws);
        out_kernel<<<np, 400, 0, stream>>>(ws, Wc, bc, outp);
    } else {
        conv_kernel<<<np, 320, 0, stream>>>(feat, rho, theta, mask, mu_rho,
                                            mu_theta, sig_rho, sig_theta,
                                            Wc, bc, outp);
    }
}

// Round 3
// 54.031 us; speedup vs baseline: 1.8783x; 1.8783x over previous
//
#include <hip/hip_runtime.h>

#define V 64
#define W 5
#define G 80
#define O 80
#define NROT 16
#define EPSV 1e-5f
#define NLOG2E (-1.4426950408889634f)

// One block per (b,n) point. 640 threads = 10 waves.
// Stage 2 mapping: g = tid % 80, jj = tid / 80 in 0..7 (k-pair 2jj, 2jj+1).
// Stage 3 mapping: tid < 400 -> one (w,o) output each, single pass.
__global__ __launch_bounds__(640) void conv_kernel(
    const float* __restrict__ feat,      // [NP][V][W]
    const float* __restrict__ rho,       // [NP][V]
    const float* __restrict__ theta,     // [NP][V]
    const float* __restrict__ mask,      // [NP][V]
    const float* __restrict__ mu_rho,    // [W][G]
    const float* __restrict__ mu_theta,  // [W][G]
    const float* __restrict__ sig_rho,   // [W][G]
    const float* __restrict__ sig_theta, // [W][G]
    const float* __restrict__ Wc,        // [W][G][O]
    const float* __restrict__ bc,        // [W][O]
    float* __restrict__ out)             // [NP][W][O]
{
    __shared__ float s_rhom[V][2];         // (rho, mask? 0 : -1e30)
    __shared__ float s_featT[V][8];        // feat[v][w], padded
    __shared__ float s_th[V][NROT];        // rotated theta per (v,k)
    __shared__ float s_desc[W][G][NROT];   // descriptor

    const int tid = threadIdx.x;
    const int p = blockIdx.x;
    const int g = tid % G;    // 0..79
    const int jj = tid / G;   // 0..7 (k-pair index)

    // ---- stage 1: stage point data into LDS ----
    if (tid < V) {
        s_rhom[tid][0] = rho[p * V + tid];
        s_rhom[tid][1] = (mask[p * V + tid] != 0.0f) ? 0.0f : -1e30f;
    }
    if (tid < V * W) {
        int v = tid / W, w = tid % W;
        s_featT[v][w] = feat[p * V * W + tid];
    }
    const float kstep = 0.39269908169872414f;      // 2*pi/16
    const float two_pi = 6.283185307179586f;
    const float inv_two_pi = 0.15915494309189535f;
    for (int i = tid; i < V * NROT; i += 640) {
        int v = i >> 4, k = i & 15;
        float x = theta[p * V + v] + (float)k * kstep;
        x = x - floorf(x * inv_two_pi) * two_pi;   // jnp.mod(x, 2pi)
        s_th[v][k] = x;
    }

    // uniformity check: are mu/sigma rows identical across W?
    // rows 1..4 each checked twice (jj and jj+4).
    const int wchk = 1 + (jj & 3);
    int pred = (mu_rho  [wchk * G + g] == mu_rho  [g]) &&
               (mu_theta[wchk * G + g] == mu_theta[g]) &&
               (sig_rho [wchk * G + g] == sig_rho [g]) &&
               (sig_theta[wchk * G + g] == sig_theta[g]);
    const int uni = __syncthreads_and(pred);   // doubles as stage-1 barrier

    // ---- stage 2: gaussian accumulation -> desc (k-pair per thread) ----
    if (uni) {
        // fast path: gaussian independent of w -> one exp serves 5 channels
        const float mu_r = mu_rho[g];
        const float sr   = sig_rho[g];
        const float c_sr = NLOG2E / (sr * sr + EPSV);
        const float mu_t = mu_theta[g];
        const float st   = sig_theta[g];
        const float c_st = NLOG2E / (st * st + EPSV);

        float den0 = 0.f, den1 = 0.f;
        float num0[5], num1[5];
        #pragma unroll
        for (int w = 0; w < W; ++w) { num0[w] = 0.f; num1[w] = 0.f; }

        #pragma unroll 4
        for (int v = 0; v < V; ++v) {
            float2 rm = *(const float2*)(&s_rhom[v][0]);
            float dr = rm.x - mu_r;
            float argr = fmaf(dr * dr, c_sr, rm.y);   // rho part + mask fold
            float4 fA = *(const float4*)(&s_featT[v][0]);
            float f4v = s_featT[v][4];
            float2 th2 = *(const float2*)(&s_th[v][jj * 2]);

            float t0 = th2.x - mu_t;
            float e0 = __builtin_amdgcn_exp2f(fmaf(t0 * t0, c_st, argr));
            den0 += e0;
            num0[0] = fmaf(e0, fA.x, num0[0]);
            num0[1] = fmaf(e0, fA.y, num0[1]);
            num0[2] = fmaf(e0, fA.z, num0[2]);
            num0[3] = fmaf(e0, fA.w, num0[3]);
            num0[4] = fmaf(e0, f4v,  num0[4]);

            float t1 = th2.y - mu_t;
            float e1 = __builtin_amdgcn_exp2f(fmaf(t1 * t1, c_st, argr));
            den1 += e1;
            num1[0] = fmaf(e1, fA.x, num1[0]);
            num1[1] = fmaf(e1, fA.y, num1[1]);
            num1[2] = fmaf(e1, fA.z, num1[2]);
            num1[3] = fmaf(e1, fA.w, num1[3]);
            num1[4] = fmaf(e1, f4v,  num1[4]);
        }
        float rd0 = __builtin_amdgcn_rcpf(den0 + EPSV);
        float rd1 = __builtin_amdgcn_rcpf(den1 + EPSV);
        #pragma unroll
        for (int w = 0; w < W; ++w) {
            float2 dv = make_float2(num0[w] * rd0, num1[w] * rd1);
            *(float2*)(&s_desc[w][g][jj * 2]) = dv;
        }
    } else {
        // generic path: per-w gaussians (correctness fallback)
        #pragma unroll 1
        for (int w = 0; w < W; ++w) {
            const float mu_r = mu_rho[w * G + g];
            const float sr   = sig_rho[w * G + g];
            const float c_sr = NLOG2E / (sr * sr + EPSV);
            const float mu_t = mu_theta[w * G + g];
            const float st   = sig_theta[w * G + g];
            const float c_st = NLOG2E / (st * st + EPSV);
            float den0 = 0.f, den1 = 0.f, nm0 = 0.f, nm1 = 0.f;
            for (int v = 0; v < V; ++v) {
                float2 rm = *(const float2*)(&s_rhom[v][0]);
                float dr = rm.x - mu_r;
                float argr = fmaf(dr * dr, c_sr, rm.y);
                float fw = s_featT[v][w];
                float2 th2 = *(const float2*)(&s_th[v][jj * 2]);
                float t0 = th2.x - mu_t;
                float e0 = __builtin_amdgcn_exp2f(fmaf(t0 * t0, c_st, argr));
                den0 += e0; nm0 = fmaf(e0, fw, nm0);
                float t1 = th2.y - mu_t;
                float e1 = __builtin_amdgcn_exp2f(fmaf(t1 * t1, c_st, argr));
                den1 += e1; nm1 = fmaf(e1, fw, nm1);
            }
            float2 dv;
            dv.x = nm0 * __builtin_amdgcn_rcpf(den0 + EPSV);
            dv.y = nm1 * __builtin_amdgcn_rcpf(den1 + EPSV);
            *(float2*)(&s_desc[w][g][jj * 2]) = dv;
        }
    }

    __syncthreads();

    // ---- stage 3: out[w,o] = max_k (sum_g desc[w,g,k]*Wc[w,g,o]) + bc[w,o] ----
    if (tid < W * O) {
        const int w = tid / O, o = tid % O;
        const float* wp = Wc + w * G * O + o;
        float acc[NROT];
        #pragma unroll
        for (int k = 0; k < NROT; ++k) acc[k] = 0.f;
        #pragma unroll 4
        for (int gg = 0; gg < G; ++gg) {
            float wcv = wp[gg * O];                 // coalesced over o
            const float* dp = &s_desc[w][gg][0];    // broadcast over o-lanes
            float4 d0 = *(const float4*)(dp + 0);
            float4 d1 = *(const float4*)(dp + 4);
            float4 d2 = *(const float4*)(dp + 8);
            float4 d3 = *(const float4*)(dp + 12);
            acc[0]  = fmaf(d0.x, wcv, acc[0]);
            acc[1]  = fmaf(d0.y, wcv, acc[1]);
            acc[2]  = fmaf(d0.z, wcv, acc[2]);
            acc[3]  = fmaf(d0.w, wcv, acc[3]);
            acc[4]  = fmaf(d1.x, wcv, acc[4]);
            acc[5]  = fmaf(d1.y, wcv, acc[5]);
            acc[6]  = fmaf(d1.z, wcv, acc[6]);
            acc[7]  = fmaf(d1.w, wcv, acc[7]);
            acc[8]  = fmaf(d2.x, wcv, acc[8]);
            acc[9]  = fmaf(d2.y, wcv, acc[9]);
            acc[10] = fmaf(d2.z, wcv, acc[10]);
            acc[11] = fmaf(d2.w, wcv, acc[11]);
            acc[12] = fmaf(d3.x, wcv, acc[12]);
            acc[13] = fmaf(d3.y, wcv, acc[13]);
            acc[14] = fmaf(d3.z, wcv, acc[14]);
            acc[15] = fmaf(d3.w, wcv, acc[15]);
        }
        float m = acc[0];
        #pragma unroll
        for (int k = 1; k < NROT; ++k) m = fmaxf(m, acc[k]);
        out[p * W * O + tid] = m + bc[tid];
    }
}

extern "C" void kernel_launch(void* const* d_in, const int* in_sizes, int n_in,
                              void* d_out, int out_size, void* d_ws, size_t ws_size,
                              hipStream_t stream) {
    const float* feat      = (const float*)d_in[0];
    const float* rho       = (const float*)d_in[1];
    const float* theta     = (const float*)d_in[2];
    const float* mask      = (const float*)d_in[3];
    const float* mu_rho    = (const float*)d_in[4];
    const float* mu_theta  = (const float*)d_in[5];
    const float* sig_rho   = (const float*)d_in[6];
    const float* sig_theta = (const float*)d_in[7];
    const float* Wc        = (const float*)d_in[8];
    const float* bc        = (const float*)d_in[9];
    float* outp            = (float*)d_out;

    const int np = in_sizes[1] / V;   // B*N points (rho is [B,N,V])
    conv_kernel<<<np, 640, 0, stream>>>(feat, rho, theta, mask, mu_rho, mu_theta,
                                        sig_rho, sig_theta, Wc, bc, outp);
}

// Round 4
// 44.529 us; speedup vs baseline: 2.2791x; 1.2134x over previous
//
#include <hip/hip_runtime.h>

#define V 64
#define W 5
#define G 80
#define O 80
#define NROT 16
#define GPAD 96
#define EPSV 1e-5f
#define NLOG2E (-1.4426950408889634f)

using bf16x8 = __attribute__((ext_vector_type(8))) short;
using f32x4  = __attribute__((ext_vector_type(4))) float;

__device__ __forceinline__ unsigned short f2bf(float x) {
    unsigned u = __float_as_uint(x);
    unsigned r = (u + 0x7FFFu + ((u >> 16) & 1u)) >> 16;   // RNE
    return (unsigned short)r;
}

// ============================================================================
// Setup: pack Wc into bf16 B-fragments for mfma_f32_16x16x32_bf16.
// frag f = (w*3 + ks)*5 + nt ; lane l holds B[g = ks*32+(l>>4)*8+i][o = nt*16+(l&15)]
// wsB layout: [75 frags][64 lanes][8 shorts]
// ============================================================================
__global__ __launch_bounds__(64) void pack_wc_kernel(
    const float* __restrict__ Wc, unsigned short* __restrict__ wsB)
{
    const int f = blockIdx.x;      // 0..74
    const int l = threadIdx.x;     // 0..63
    const int w  = f / 15;
    const int r  = f % 15;
    const int ks = r / 5;
    const int nt = r % 5;
    const int g0 = ks * 32 + ((l >> 4) << 3);
    const int o  = nt * 16 + (l & 15);
    unsigned short v[8];
    #pragma unroll
    for (int i = 0; i < 8; ++i) {
        int g = g0 + i;
        float x = (g < G) ? Wc[(w * G + g) * O + o] : 0.0f;
        v[i] = f2bf(x);
    }
    unsigned short* dst = wsB + ((size_t)f * 64 + l) * 8;
    *(uint4*)dst = *(const uint4*)v;
}

// ============================================================================
// Main kernel: one block per point, 320 threads = 5 waves.
// Stage 2: thread (g = tid%80, j = tid/80) owns k-quad j*4..j*4+3.
// Stage 3: wave ww = w; MFMA over 5 n-tiles x 3 k-steps.
// ============================================================================
__global__ __launch_bounds__(320) void conv_kernel(
    const float* __restrict__ feat,      // [NP][V][W]
    const float* __restrict__ rho,       // [NP][V]
    const float* __restrict__ theta,     // [NP][V]
    const float* __restrict__ mask,      // [NP][V]
    const float* __restrict__ mu_rho,    // [W][G]
    const float* __restrict__ mu_theta,  // [W][G]
    const float* __restrict__ sig_rho,   // [W][G]
    const float* __restrict__ sig_theta, // [W][G]
    const unsigned short* __restrict__ wsB,  // packed bf16 B-frags
    const float* __restrict__ bc,        // [W][O]
    float* __restrict__ out)             // [NP][W][O]
{
    __shared__ float s_pt[V][8];                      // f0..f4, rho, mrk, theta
    __shared__ unsigned short s_descT[W][NROT][GPAD]; // bf16 desc^T, K-padded
    __shared__ float s_red[W][64];                    // per-wave max reduce

    const int tid = threadIdx.x;
    const int p = blockIdx.x;
    const int g = tid % G;   // 0..79
    const int j = tid / G;   // 0..3 (k-quad)

    // ---- stage 1: stage packed point data; zero the g-pad of descT ----
    if (tid < V * W) {
        int v = tid / W, w = tid % W;
        s_pt[v][w] = feat[p * V * W + tid];
    }
    if (tid < V) {
        s_pt[tid][5] = rho[p * V + tid];
        s_pt[tid][6] = (mask[p * V + tid] != 0.0f) ? 0.0f : -1e30f;
        s_pt[tid][7] = theta[p * V + tid];
    }
    // pad region: shorts [*][*][80..96) -> u32 cols 40..47 of 48-u32 rows
    for (int i = tid; i < W * NROT * 8; i += 320) {
        int row = i >> 3, col = 40 + (i & 7);
        ((unsigned*)s_descT)[row * 48 + col] = 0u;
    }

    const int wchk = 1 + j;
    int pred = (mu_rho  [wchk * G + g] == mu_rho  [g]) &&
               (mu_theta[wchk * G + g] == mu_theta[g]) &&
               (sig_rho [wchk * G + g] == sig_rho [g]) &&
               (sig_theta[wchk * G + g] == sig_theta[g]);
    const int uni = __syncthreads_and(pred);

    const float kstep = 0.39269908169872414f;      // 2*pi/16
    const float two_pi = 6.283185307179586f;
    const float inv_two_pi = 0.15915494309189535f;
    float koff[4];
    #pragma unroll
    for (int kk = 0; kk < 4; ++kk) koff[kk] = (float)(j * 4 + kk) * kstep;

    // ---- stage 2: gaussian accumulation -> descT (bf16) ----
    if (uni) {
        const float mu_r = mu_rho[g];
        const float sr   = sig_rho[g];
        const float c_sr = NLOG2E / (sr * sr + EPSV);
        const float mu_t = mu_theta[g];
        const float st   = sig_theta[g];
        const float c_st = NLOG2E / (st * st + EPSV);

        float den[4] = {0.f, 0.f, 0.f, 0.f};
        float num[5][4];
        #pragma unroll
        for (int w = 0; w < W; ++w)
            #pragma unroll
            for (int kk = 0; kk < 4; ++kk) num[w][kk] = 0.f;

        #pragma unroll 2
        for (int v = 0; v < V; ++v) {
            float4 flo = *(const float4*)(&s_pt[v][0]);   // f0..f3
            float4 fhi = *(const float4*)(&s_pt[v][4]);   // f4, rho, mrk, theta
            float dr = fhi.y - mu_r;
            float argr = fmaf(dr * dr, c_sr, fhi.z);      // rho part + mask fold
            #pragma unroll
            for (int kk = 0; kk < 4; ++kk) {
                float x = fhi.w + koff[kk];
                x = x - floorf(x * inv_two_pi) * two_pi;  // jnp.mod(x, 2pi)
                float t = x - mu_t;
                float e = __builtin_amdgcn_exp2f(fmaf(t * t, c_st, argr));
                den[kk] += e;
                num[0][kk] = fmaf(e, flo.x, num[0][kk]);
                num[1][kk] = fmaf(e, flo.y, num[1][kk]);
                num[2][kk] = fmaf(e, flo.z, num[2][kk]);
                num[3][kk] = fmaf(e, flo.w, num[3][kk]);
                num[4][kk] = fmaf(e, fhi.x, num[4][kk]);
            }
        }
        float rd[4];
        #pragma unroll
        for (int kk = 0; kk < 4; ++kk)
            rd[kk] = __builtin_amdgcn_rcpf(den[kk] + EPSV);
        #pragma unroll
        for (int w = 0; w < W; ++w)
            #pragma unroll
            for (int kk = 0; kk < 4; ++kk)
                s_descT[w][j * 4 + kk][g] = f2bf(num[w][kk] * rd[kk]);
    } else {
        // generic path: per-w gaussians
        #pragma unroll 1
        for (int w = 0; w < W; ++w) {
            const float mu_r = mu_rho[w * G + g];
            const float sr   = sig_rho[w * G + g];
            const float c_sr = NLOG2E / (sr * sr + EPSV);
            const float mu_t = mu_theta[w * G + g];
            const float st   = sig_theta[w * G + g];
            const float c_st = NLOG2E / (st * st + EPSV);
            float den[4] = {0.f, 0.f, 0.f, 0.f};
            float nm[4]  = {0.f, 0.f, 0.f, 0.f};
            for (int v = 0; v < V; ++v) {
                float4 flo = *(const float4*)(&s_pt[v][0]);
                float4 fhi = *(const float4*)(&s_pt[v][4]);
                float fw = (w < 4) ? ((const float*)&flo)[w] : fhi.x;
                float dr = fhi.y - mu_r;
                float argr = fmaf(dr * dr, c_sr, fhi.z);
                #pragma unroll
                for (int kk = 0; kk < 4; ++kk) {
                    float x = fhi.w + koff[kk];
                    x = x - floorf(x * inv_two_pi) * two_pi;
                    float t = x - mu_t;
                    float e = __builtin_amdgcn_exp2f(fmaf(t * t, c_st, argr));
                    den[kk] += e;
                    nm[kk] = fmaf(e, fw, nm[kk]);
                }
            }
            #pragma unroll
            for (int kk = 0; kk < 4; ++kk)
                s_descT[w][j * 4 + kk][g] =
                    f2bf(nm[kk] * __builtin_amdgcn_rcpf(den[kk] + EPSV));
        }
    }

    __syncthreads();

    // ---- stage 3: MFMA  C[16k x 80o] = descT[w]^ * Wc[w], then max over k ----
    {
        const int ww = tid >> 6;     // wave id = w (0..4)
        const int l  = tid & 63;

        // A-frags: lane l holds A[m = l&15][g = ks*32 + (l>>4)*8 + i]
        bf16x8 afrag[3];
        #pragma unroll
        for (int ks = 0; ks < 3; ++ks)
            afrag[ks] = *(const bf16x8*)(&s_descT[ww][l & 15]
                                                [ks * 32 + ((l >> 4) << 3)]);

        #pragma unroll
        for (int nt = 0; nt < 5; ++nt) {
            f32x4 acc = {0.f, 0.f, 0.f, 0.f};
            #pragma unroll
            for (int ks = 0; ks < 3; ++ks) {
                const unsigned short* bp =
                    wsB + ((size_t)(((ww * 3 + ks) * 5 + nt) * 64 + l)) * 8;
                bf16x8 bfrag = *(const bf16x8*)bp;
                acc = __builtin_amdgcn_mfma_f32_16x16x32_bf16(
                          afrag[ks], bfrag, acc, 0, 0, 0);
            }
            // lane l holds D[m=(l>>4)*4+i][o = nt*16 + (l&15)]; max over m
            float m1 = fmaxf(fmaxf(acc[0], acc[1]), fmaxf(acc[2], acc[3]));
            s_red[ww][l] = m1;
            float r0 = s_red[ww][l & 15];
            float r1 = s_red[ww][(l & 15) + 16];
            float r2 = s_red[ww][(l & 15) + 32];
            float r3 = s_red[ww][(l & 15) + 48];
            float mx = fmaxf(fmaxf(r0, r1), fmaxf(r2, r3));
            if (l < 16) {
                int oo = nt * 16 + l;
                out[p * (W * O) + ww * O + oo] = mx + bc[ww * O + oo];
            }
        }
    }
}

extern "C" void kernel_launch(void* const* d_in, const int* in_sizes, int n_in,
                              void* d_out, int out_size, void* d_ws, size_t ws_size,
                              hipStream_t stream) {
    const float* feat      = (const float*)d_in[0];
    const float* rho       = (const float*)d_in[1];
    const float* theta     = (const float*)d_in[2];
    const float* mask      = (const float*)d_in[3];
    const float* mu_rho    = (const float*)d_in[4];
    const float* mu_theta  = (const float*)d_in[5];
    const float* sig_rho   = (const float*)d_in[6];
    const float* sig_theta = (const float*)d_in[7];
    const float* Wc        = (const float*)d_in[8];
    const float* bc        = (const float*)d_in[9];
    float* outp            = (float*)d_out;

    const int np = in_sizes[1] / V;   // B*N points
    unsigned short* wsB = (unsigned short*)d_ws;   // 75*64*8 shorts = 76.8 KB

    pack_wc_kernel<<<75, 64, 0, stream>>>(Wc, wsB);
    conv_kernel<<<np, 320, 0, stream>>>(feat, rho, theta, mask, mu_rho, mu_theta,
                                        sig_rho, sig_theta, wsB, bc, outp);
}